// Round 17
// baseline (135.934 us; speedup 1.0000x reference)
//
#include <hip/hip_runtime.h>

// GNN encoder, B=256, N=32, F=256, fully-connected edges, 2 passes.
// R17 = R16 edge (44.4us, 32x32x16) + mlp v3: 16-row tiles, grid 512,
// <=128 VGPR per wave (e1 split into 2 groups) -> 4 waves/SIMD.

typedef short bf16x8 __attribute__((ext_vector_type(8)));
typedef float f32x4 __attribute__((ext_vector_type(4)));
typedef float f32x16 __attribute__((ext_vector_type(16)));
typedef unsigned short ushort_t;

__device__ __forceinline__ unsigned short f2bf(float f) {
    unsigned u = __float_as_uint(f);
    u += 0x7fff + ((u >> 16) & 1);   // RNE
    return (unsigned short)(u >> 16);
}
__device__ __forceinline__ float lo16f(unsigned w) { return __uint_as_float(w << 16); }
__device__ __forceinline__ float hi16f(unsigned w) { return __uint_as_float(w & 0xffff0000u); }
__device__ __forceinline__ unsigned cvt_pk_bf16(float lo, float hi) {
    unsigned r;
    asm volatile("v_cvt_pk_bf16_f32 %0, %1, %2" : "=v"(r) : "v"(lo), "v"(hi));
    return r;
}
__device__ __forceinline__ void gload16(const void* g, void* l) {
    __builtin_amdgcn_global_load_lds(
        (const __attribute__((address_space(1))) void*)g,
        (__attribute__((address_space(3))) void*)l, 16, 0, 0);
}
__device__ __forceinline__ void soft_barrier() {
    asm volatile("s_waitcnt lgkmcnt(0)" ::: "memory");
    __builtin_amdgcn_sched_barrier(0);
    __builtin_amdgcn_s_barrier();
}

// ---------------------------------------------------------------------------
// Weight prep (blocks 0..55) + x conversion (blocks 56..1079), merged.
// Weight image: idx = kq*8192 + n*32 + (kc ^ ((n>>1)&3))*8 + (k&7), kq=k>>5.
__global__ __launch_bounds__(256) void prep_all(
    const float* __restrict__ w_in1, const float* __restrict__ w_in2,
    const float* __restrict__ w_e1,  const float* __restrict__ w_e2,
    const float* __restrict__ w_n1,  const float* __restrict__ w_n2,
    ushort_t* __restrict__ dst,
    const float* __restrict__ x, ushort_t* __restrict__ xb)
{
    __shared__ ushort_t tile[32][264];
    const int t = threadIdx.x;
    if (blockIdx.x >= 56) {
        const int i = (blockIdx.x - 56) * 256 + t;
        const float4* p = (const float4*)x + (size_t)i * 2;
        float4 a = p[0], b = p[1];
        ushort4 o0 = make_ushort4(f2bf(a.x), f2bf(a.y), f2bf(a.z), f2bf(a.w));
        ushort4 o1 = make_ushort4(f2bf(b.x), f2bf(b.y), f2bf(b.z), f2bf(b.w));
        ((ushort4*)xb)[(size_t)i * 2]     = o0;
        ((ushort4*)xb)[(size_t)i * 2 + 1] = o1;
        return;
    }
    const int wid = blockIdx.x >> 3;   // 0..6
    const int kb  = blockIdx.x & 7;
    const float* src;
    switch (wid) {
        case 0: src = w_in1; break;
        case 1: src = w_in2; break;
        case 2: src = w_e1; break;              // top half (send side)
        case 3: src = w_e1 + 65536; break;      // bottom half (recv side)
        case 4: src = w_e2; break;
        case 5: src = w_n1; break;
        default: src = w_n2; break;
    }
#pragma unroll
    for (int k0 = 0; k0 < 32; k0++)
        tile[k0][t] = f2bf(src[(size_t)(kb * 32 + k0) * 256 + t]);  // coalesced
    __syncthreads();
    ushort_t* base = dst + wid * 65536 + kb * 8192 + t * 32;
    const int sw = (t >> 1) & 3;
#pragma unroll
    for (int kc = 0; kc < 4; kc++) {
        union { uint4 q; ushort_t u[8]; } w;
#pragma unroll
        for (int ko = 0; ko < 8; ko++) w.u[ko] = tile[kc * 8 + ko][t];
        *(uint4*)&base[(kc ^ sw) * 8] = w.q;
    }
}

// ---------------------------------------------------------------------------
// Fused MLP chain v3: 512 blocks x 512 thr (8 waves), M=16 rows per block,
// <=128 VGPR -> 4 waves/SIMD. A-tiles [16][256] bf16 in LDS, granule swizzle:
//   off = r*256 + ((kc ^ (r&7))*8) + (k&7), kc = k>>3, r = 0..15.
// Swapped MFMA: acc = mfma(Wfrag, Xfrag) -> lane holds 4 k-contiguous outputs
// for row m = lane&15. B prefetch depth 2 (rolling bq[3][2]).

// one 32-col slice: A(src LDS) @ W[, n0..n0+32) -> acc, then emit via EMIT
template <typename EMIT>
__device__ __forceinline__ void slice32(
    const ushort_t* __restrict__ wimg, const ushort_t* __restrict__ As,
    const int n0, const int lr, const int lg, EMIT&& emit)
{
    int boffs[2];
#pragma unroll
    for (int fn = 0; fn < 2; fn++) {
        const int n = n0 + fn * 16 + lr;
        boffs[fn] = n * 32 + ((lg ^ ((lr >> 1) & 3)) * 8);
    }
    bf16x8 bq[3][2];
#pragma unroll
    for (int fn = 0; fn < 2; fn++) bq[0][fn] = *(const bf16x8*)&wimg[boffs[fn]];
#pragma unroll
    for (int fn = 0; fn < 2; fn++) bq[1][fn] = *(const bf16x8*)&wimg[8192 + boffs[fn]];
    f32x4 acc[2] = {};
#pragma unroll
    for (int kb = 0; kb < 8; kb++) {
        if (kb < 6)
#pragma unroll
            for (int fn = 0; fn < 2; fn++)
                bq[(kb + 2) % 3][fn] = *(const bf16x8*)&wimg[(kb + 2) * 8192 + boffs[fn]];
        const int r = lr;
        bf16x8 af = *(const bf16x8*)&As[r * 256 + (((kb * 4 + lg) ^ (r & 7)) * 8)];
#pragma unroll
        for (int fn = 0; fn < 2; fn++)
            acc[fn] = __builtin_amdgcn_mfma_f32_16x16x32_bf16(
                bq[kb % 3][fn], af, acc[fn], 0, 0, 0);
    }
    emit(acc);
}

template <int THREE>
__global__ __launch_bounds__(512, 4) void mlp_chain(
    const ushort_t* __restrict__ in,
    const ushort_t* __restrict__ wA, const float* __restrict__ bA,
    const ushort_t* __restrict__ wB, const float* __restrict__ bB,
    const ushort_t* __restrict__ wE, const float* __restrict__ bE,
    void* __restrict__ out)
{
    __shared__ ushort_t A0[16 * 256];
    __shared__ ushort_t A1[16 * 256];
    const int m0 = blockIdx.x * 16;
    const int t = threadIdx.x;
    const int lane = t & 63, w = t >> 6;
    const int lr = lane & 15, lg = lane >> 4;

    // stage input tile: 16 rows x 256 = 4096 elems = 512 thr x 8
    {
        const int r0 = t >> 5, p0 = t & 31;
        gload16(in + (size_t)(m0 + r0) * 256 + ((p0 ^ (r0 & 7)) * 8), &A0[t * 8]);
    }
    __syncthreads();

    // layer A -> A1 (relu, bf16, swizzled)
    {
        const int n0 = w * 32;
        float4 b4[2];
#pragma unroll
        for (int fn = 0; fn < 2; fn++) b4[fn] = *(const float4*)&bA[n0 + fn * 16 + lg * 4];
        slice32(wA, A0, n0, lr, lg, [&](f32x4 (&acc)[2]) {
#pragma unroll
            for (int fn = 0; fn < 2; fn++) {
                const int k0 = n0 + fn * 16 + lg * 4;
                const int kc = k0 >> 3, kj = k0 & 7;
                const int m = lr;
                float v0 = fmaxf(acc[fn][0] + b4[fn].x, 0.f);
                float v1 = fmaxf(acc[fn][1] + b4[fn].y, 0.f);
                float v2 = fmaxf(acc[fn][2] + b4[fn].z, 0.f);
                float v3 = fmaxf(acc[fn][3] + b4[fn].w, 0.f);
                uint2 q = { cvt_pk_bf16(v0, v1), cvt_pk_bf16(v2, v3) };
                *(uint2*)&A1[m * 256 + ((kc ^ (m & 7)) * 8) + kj] = q;
            }
        });
    }
    __syncthreads();

    if constexpr (THREE) {
        // layer B -> A0
        {
            const int n0 = w * 32;
            float4 b4[2];
#pragma unroll
            for (int fn = 0; fn < 2; fn++) b4[fn] = *(const float4*)&bB[n0 + fn * 16 + lg * 4];
            slice32(wB, A1, n0, lr, lg, [&](f32x4 (&acc)[2]) {
#pragma unroll
                for (int fn = 0; fn < 2; fn++) {
                    const int k0 = n0 + fn * 16 + lg * 4;
                    const int kc = k0 >> 3, kj = k0 & 7;
                    const int m = lr;
                    float v0 = fmaxf(acc[fn][0] + b4[fn].x, 0.f);
                    float v1 = fmaxf(acc[fn][1] + b4[fn].y, 0.f);
                    float v2 = fmaxf(acc[fn][2] + b4[fn].z, 0.f);
                    float v3 = fmaxf(acc[fn][3] + b4[fn].w, 0.f);
                    uint2 q = { cvt_pk_bf16(v0, v1), cvt_pk_bf16(v2, v3) };
                    *(uint2*)&A0[m * 256 + ((kc ^ (m & 7)) * 8) + kj] = q;
                }
            });
        }
        __syncthreads();
        // e1: wave w covers 64 cols of [U'|V], as 2 sequential 32-col groups.
        ushort_t* UVb = (ushort_t*)out;
        const ushort_t* wimg = (w < 4) ? wE : (wE + 65536);
#pragma unroll
        for (int g = 0; g < 2; g++) {
            const int nl = (w & 3) * 64 + g * 32;     // col within 256-half
            float4 b4[2];
#pragma unroll
            for (int fn = 0; fn < 2; fn++) {
                if (w < 4) b4[fn] = *(const float4*)&bE[nl + fn * 16 + lg * 4];
                else       b4[fn] = make_float4(0.f, 0.f, 0.f, 0.f);
            }
            slice32(wimg, A0, nl, lr, lg, [&](f32x4 (&acc)[2]) {
#pragma unroll
                for (int fn = 0; fn < 2; fn++) {
                    const int nglob = (w >= 4 ? 256 : 0) + nl + fn * 16 + lg * 4;
                    const int node = m0 + lr;
                    float v0 = acc[fn][0] + b4[fn].x;
                    float v1 = acc[fn][1] + b4[fn].y;
                    float v2 = acc[fn][2] + b4[fn].z;
                    float v3 = acc[fn][3] + b4[fn].w;
                    uint2 q = { cvt_pk_bf16(v0, v1), cvt_pk_bf16(v2, v3) };
                    *(uint2*)&UVb[(size_t)node * 512 + nglob] = q;
                }
            });
        }
    } else {
        // final layer -> f32 out
        float* fo = (float*)out;
        const int n0 = w * 32;
        float4 b4[2];
#pragma unroll
        for (int fn = 0; fn < 2; fn++) b4[fn] = *(const float4*)&bB[n0 + fn * 16 + lg * 4];
        slice32(wB, A1, n0, lr, lg, [&](f32x4 (&acc)[2]) {
#pragma unroll
            for (int fn = 0; fn < 2; fn++) {
                const int col = n0 + fn * 16 + lg * 4;
                const int row = m0 + lr;
                float4 o;
                o.x = fmaxf(acc[fn][0] + b4[fn].x, 0.f);
                o.y = fmaxf(acc[fn][1] + b4[fn].y, 0.f);
                o.z = fmaxf(acc[fn][2] + b4[fn].z, 0.f);
                o.w = fmaxf(acc[fn][3] + b4[fn].w, 0.f);
                *(float4*)&fo[(size_t)row * 256 + col] = o;
            }
        });
    }
}

// ---------------------------------------------------------------------------
// Fused edge layer-2 + scatter-mean (R16: 32x32x16 MFMA, best measured).
__global__ __launch_bounds__(256, 2) void edge_fused(
    const ushort_t* __restrict__ UVb,   // [8192][512] bf16: U'(+b_e1) | V
    const ushort_t* __restrict__ WBsw,  // swizzled w_e2 image
    const float* __restrict__ b2,
    ushort_t* __restrict__ agg)         // [8192][256] bf16
{
    __shared__ ushort_t As[2][128 * 64];   // 16KB each

    const int logical = (blockIdx.x & 7) * 256 + (blockIdx.x >> 3);  // 2048%8==0
    const int bb = logical >> 3;        // batch
    const int g0 = (logical & 7) * 4;   // first receiver of the quad
    const int t = threadIdx.x;
    const int lane = t & 63;
    const int w = t >> 6;
    const int l31 = lane & 31;
    const int hg = lane >> 5;           // k half-granule select

    const int brow = t >> 1;            // 0..127
    const int kh = t & 1;
    const int jr = brow >> 5;
    const int s = brow & 31;
    const int j = g0 + jr;
    const int si = (s == 31) ? j : (s + (s >= j ? 1 : 0));
    const ushort_t* up = UVb + (size_t)(bb * 32 + si) * 512 + kh * 32;
    const ushort_t* vp = UVb + (size_t)(bb * 32 + j) * 512 + 256 + kh * 32;
    const int rs7 = brow & 7;
    int aw[4];
#pragma unroll
    for (int i = 0; i < 4; i++)
        aw[i] = brow * 64 + (((kh * 4 + i) ^ rs7) * 8);

    int abase[4];
#pragma unroll
    for (int mt = 0; mt < 4; mt++) abase[mt] = (mt * 32 + l31) * 64;
    const int r7 = l31 & 7;
    int nb32[2], nsw[2];
#pragma unroll
    for (int nt = 0; nt < 2; nt++) {
        const int n = w * 64 + nt * 32 + l31;
        nb32[nt] = n * 32;
        nsw[nt] = (n >> 1) & 3;
    }

    auto build = [&](int buf, const uint4* u, const uint4* v) {
#pragma unroll
        for (int i = 0; i < 4; i++) {
            uint4 q;
            q.x = cvt_pk_bf16(fmaxf(lo16f(u[i].x) + lo16f(v[i].x), 0.f),
                              fmaxf(hi16f(u[i].x) + hi16f(v[i].x), 0.f));
            q.y = cvt_pk_bf16(fmaxf(lo16f(u[i].y) + lo16f(v[i].y), 0.f),
                              fmaxf(hi16f(u[i].y) + hi16f(v[i].y), 0.f));
            q.z = cvt_pk_bf16(fmaxf(lo16f(u[i].z) + lo16f(v[i].z), 0.f),
                              fmaxf(hi16f(u[i].z) + hi16f(v[i].z), 0.f));
            q.w = cvt_pk_bf16(fmaxf(lo16f(u[i].w) + lo16f(v[i].w), 0.f),
                              fmaxf(hi16f(u[i].w) + hi16f(v[i].w), 0.f));
            *(uint4*)&As[buf][aw[i]] = q;
        }
    };

    auto loadB = [&](int kb, bf16x8 dst[4][2]) {
#pragma unroll
        for (int k16 = 0; k16 < 4; k16++)
#pragma unroll
            for (int nt = 0; nt < 2; nt++) {
                const int kq = kb * 2 + (k16 >> 1);
                const int kc = (k16 & 1) * 2 + hg;
                dst[k16][nt] = *(const bf16x8*)&WBsw[kq * 8192 + nb32[nt]
                                                    + ((kc ^ nsw[nt]) * 8)];
            }
    };

    {
        uint4 u[4], v[4];
#pragma unroll
        for (int i = 0; i < 4; i++) {
            u[i] = *(const uint4*)(up + i * 8);
            v[i] = *(const uint4*)(vp + i * 8);
        }
        build(0, u, v);
    }
    bf16x8 bc[4][2];
    loadB(0, bc);

    f32x16 acc[4][2] = {};

#pragma unroll
    for (int kb = 0; kb < 4; kb++) {
        const int cur = kb & 1;
        soft_barrier();
        uint4 u[4], v[4];
        if (kb < 3) {
            const ushort_t* upn = up + (kb + 1) * 64;
            const ushort_t* vpn = vp + (kb + 1) * 64;
#pragma unroll
            for (int i = 0; i < 4; i++) {
                u[i] = *(const uint4*)(upn + i * 8);
                v[i] = *(const uint4*)(vpn + i * 8);
            }
        }
        __builtin_amdgcn_s_setprio(1);
#pragma unroll
        for (int k16 = 0; k16 < 4; k16++) {
            const int goff = (((k16 * 2 + hg) ^ r7) * 8);
            bf16x8 af[4];
#pragma unroll
            for (int mt = 0; mt < 4; mt++)
                af[mt] = *(const bf16x8*)&As[cur][abase[mt] + goff];
#pragma unroll
            for (int nt = 0; nt < 2; nt++)
#pragma unroll
                for (int mt = 0; mt < 4; mt++)
                    acc[mt][nt] = __builtin_amdgcn_mfma_f32_32x32x16_bf16(
                        af[mt], bc[k16][nt], acc[mt][nt], 0, 0, 0);
        }
        __builtin_amdgcn_s_setprio(0);
        if (kb < 3) {
            loadB(kb + 1, bc);
            build(cur ^ 1, u, v);
        }
    }

    // Epilogue: bias+relu, sum 31 real slots, /31, bf16 out.
    // C/D: col = lane&31, slot = (j&3) + 8*(j>>2) + 4*hg; slot31 = reg15 hi.
#pragma unroll
    for (int nt = 0; nt < 2; nt++) {
        const int col = w * 64 + nt * 32 + l31;
        const float bvf = b2[col];
#pragma unroll
        for (int mt = 0; mt < 4; mt++) {
            float sum = 0.f;
#pragma unroll
            for (int jj = 0; jj < 16; jj++) {
                float v = fmaxf(acc[mt][nt][jj] + bvf, 0.f);
                if (!(jj == 15 && hg == 1)) sum += v;   // skip slot 31
            }
            sum += __shfl_xor(sum, 32);
            if (lane < 32)
                agg[(size_t)(bb * 32 + g0 + mt) * 256 + col] =
                    f2bf(sum * (1.0f / 31.0f));
        }
    }
}

// ---------------------------------------------------------------------------
extern "C" void kernel_launch(void* const* d_in, const int* in_sizes, int n_in,
                              void* d_out, int out_size, void* d_ws, size_t ws_size,
                              hipStream_t stream)
{
    const float* x     = (const float*)d_in[0];
    const float* w_in1 = (const float*)d_in[3];
    const float* b_in1 = (const float*)d_in[4];
    const float* w_in2 = (const float*)d_in[5];
    const float* b_in2 = (const float*)d_in[6];
    const float* w_e1  = (const float*)d_in[7];
    const float* b_e1  = (const float*)d_in[8];
    const float* w_e2  = (const float*)d_in[9];
    const float* b_e2  = (const float*)d_in[10];
    const float* w_n1  = (const float*)d_in[11];
    const float* b_n1  = (const float*)d_in[12];
    const float* w_n2  = (const float*)d_in[13];
    const float* b_n2  = (const float*)d_in[14];

    char* ws = (char*)d_ws;
    size_t off = 0;
    auto alloc = [&](size_t n) { char* p = ws + off; off += (n + 255) & ~(size_t)255; return p; };

    ushort_t* wt  = (ushort_t*)alloc(7 * 65536 * sizeof(ushort_t));
    ushort_t* xb  = (ushort_t*)alloc(8192 * 256 * 2);
    ushort_t* UVb = (ushort_t*)alloc(8192 * 512 * 2);
    ushort_t* ag  = (ushort_t*)alloc(8192 * 256 * 2);
    (void)ws_size; (void)in_sizes; (void)n_in; (void)out_size;

    prep_all<<<1080, 256, 0, stream>>>(w_in1, w_in2, w_e1, w_e2, w_n1, w_n2, wt, x, xb);

    // pass 0 front: in1 -> in2 -> e1
    mlp_chain<1><<<512, 512, 0, stream>>>(xb,
        wt + 0 * 65536, b_in1, wt + 1 * 65536, b_in2, wt + 2 * 65536, b_e1, UVb);
    edge_fused<<<2048, 256, 0, stream>>>(UVb, wt + 4 * 65536, b_e2, ag);
    // pass 1 front: n1 -> n2 -> e1
    mlp_chain<1><<<512, 512, 0, stream>>>(ag,
        wt + 5 * 65536, b_n1, wt + 6 * 65536, b_n2, wt + 2 * 65536, b_e1, UVb);
    edge_fused<<<2048, 256, 0, stream>>>(UVb, wt + 4 * 65536, b_e2, ag);
    // final: n1 -> n2 (f32 out)
    mlp_chain<0><<<512, 512, 0, stream>>>(ag,
        wt + 5 * 65536, b_n1, wt + 6 * 65536, b_n2, nullptr, nullptr, d_out);
}

// Round 18
// 123.762 us; speedup vs baseline: 1.0983x; 1.0983x over previous
//
#include <hip/hip_runtime.h>

// GNN encoder, B=256, N=32, F=256, fully-connected edges, 2 passes.
// R18 = R16 exact revert (best measured: 124.05us).
// edge: 32x32x16 MFMA, 128x256 block, BK=64 dbuf, soft barrier, setprio.
// mlp: 512-thr chains (2 waves/SIMD), depth-2 rolling B prefetch.

typedef short bf16x8 __attribute__((ext_vector_type(8)));
typedef float f32x4 __attribute__((ext_vector_type(4)));
typedef float f32x16 __attribute__((ext_vector_type(16)));
typedef unsigned short ushort_t;

__device__ __forceinline__ unsigned short f2bf(float f) {
    unsigned u = __float_as_uint(f);
    u += 0x7fff + ((u >> 16) & 1);   // RNE
    return (unsigned short)(u >> 16);
}
__device__ __forceinline__ float lo16f(unsigned w) { return __uint_as_float(w << 16); }
__device__ __forceinline__ float hi16f(unsigned w) { return __uint_as_float(w & 0xffff0000u); }
__device__ __forceinline__ unsigned cvt_pk_bf16(float lo, float hi) {
    unsigned r;
    asm volatile("v_cvt_pk_bf16_f32 %0, %1, %2" : "=v"(r) : "v"(lo), "v"(hi));
    return r;
}
__device__ __forceinline__ void gload16(const void* g, void* l) {
    __builtin_amdgcn_global_load_lds(
        (const __attribute__((address_space(1))) void*)g,
        (__attribute__((address_space(3))) void*)l, 16, 0, 0);
}
__device__ __forceinline__ void soft_barrier() {
    asm volatile("s_waitcnt lgkmcnt(0)" ::: "memory");
    __builtin_amdgcn_sched_barrier(0);
    __builtin_amdgcn_s_barrier();
}

// ---------------------------------------------------------------------------
// Weight prep (blocks 0..55) + x conversion (blocks 56..1079), merged.
// Weight image: idx = kq*8192 + n*32 + (kc ^ ((n>>1)&3))*8 + (k&7), kq=k>>5.
__global__ __launch_bounds__(256) void prep_all(
    const float* __restrict__ w_in1, const float* __restrict__ w_in2,
    const float* __restrict__ w_e1,  const float* __restrict__ w_e2,
    const float* __restrict__ w_n1,  const float* __restrict__ w_n2,
    ushort_t* __restrict__ dst,
    const float* __restrict__ x, ushort_t* __restrict__ xb)
{
    __shared__ ushort_t tile[32][264];
    const int t = threadIdx.x;
    if (blockIdx.x >= 56) {
        const int i = (blockIdx.x - 56) * 256 + t;
        const float4* p = (const float4*)x + (size_t)i * 2;
        float4 a = p[0], b = p[1];
        ushort4 o0 = make_ushort4(f2bf(a.x), f2bf(a.y), f2bf(a.z), f2bf(a.w));
        ushort4 o1 = make_ushort4(f2bf(b.x), f2bf(b.y), f2bf(b.z), f2bf(b.w));
        ((ushort4*)xb)[(size_t)i * 2]     = o0;
        ((ushort4*)xb)[(size_t)i * 2 + 1] = o1;
        return;
    }
    const int wid = blockIdx.x >> 3;   // 0..6
    const int kb  = blockIdx.x & 7;
    const float* src;
    switch (wid) {
        case 0: src = w_in1; break;
        case 1: src = w_in2; break;
        case 2: src = w_e1; break;              // top half (send side)
        case 3: src = w_e1 + 65536; break;      // bottom half (recv side)
        case 4: src = w_e2; break;
        case 5: src = w_n1; break;
        default: src = w_n2; break;
    }
#pragma unroll
    for (int k0 = 0; k0 < 32; k0++)
        tile[k0][t] = f2bf(src[(size_t)(kb * 32 + k0) * 256 + t]);  // coalesced
    __syncthreads();
    ushort_t* base = dst + wid * 65536 + kb * 8192 + t * 32;
    const int sw = (t >> 1) & 3;
#pragma unroll
    for (int kc = 0; kc < 4; kc++) {
        union { uint4 q; ushort_t u[8]; } w;
#pragma unroll
        for (int ko = 0; ko < 8; ko++) w.u[ko] = tile[kc * 8 + ko][t];
        *(uint4*)&base[(kc ^ sw) * 8] = w.q;
    }
}

// ---------------------------------------------------------------------------
// Fused MLP chain, 512 threads (8 waves, 2 waves/SIMD). Wave w owns a 32-col
// slice (hidden/final layers) or a 64-col slice of 512 (e1 layer).
// A-tiles [32][256] bf16 in LDS, granule swizzle:
//   off = r*256 + ((kc ^ (r&7))*8) + (k&7), kc = k>>3.
// Swapped MFMA: acc = mfma(Wfrag, Xfrag) -> lane holds 4 k-contiguous outputs.
// B prefetch depth 2 (rolling bq[3][..], statically indexed via full unroll).

__device__ __forceinline__ void layer_to_lds(
    const ushort_t* __restrict__ wimg, const float* __restrict__ bias,
    const ushort_t* __restrict__ As, ushort_t* __restrict__ Ad,
    const int w, const int lr, const int lg)
{
    int boffs[2]; float4 b4[2];
#pragma unroll
    for (int fn = 0; fn < 2; fn++) {
        const int n = w * 32 + fn * 16 + lr;
        boffs[fn] = n * 32 + ((lg ^ ((lr >> 1) & 3)) * 8);
        b4[fn] = *(const float4*)&bias[w * 32 + fn * 16 + lg * 4];
    }
    bf16x8 bq[3][2];
#pragma unroll
    for (int fn = 0; fn < 2; fn++) bq[0][fn] = *(const bf16x8*)&wimg[boffs[fn]];
#pragma unroll
    for (int fn = 0; fn < 2; fn++) bq[1][fn] = *(const bf16x8*)&wimg[8192 + boffs[fn]];
    f32x4 acc[2][2] = {};
#pragma unroll
    for (int kb = 0; kb < 8; kb++) {
        if (kb < 6)
#pragma unroll
            for (int fn = 0; fn < 2; fn++)
                bq[(kb + 2) % 3][fn] = *(const bf16x8*)&wimg[(kb + 2) * 8192 + boffs[fn]];
        bf16x8 af[2];
#pragma unroll
        for (int fm = 0; fm < 2; fm++) {
            const int r = fm * 16 + lr;
            af[fm] = *(const bf16x8*)&As[r * 256 + (((kb * 4 + lg) ^ (r & 7)) * 8)];
        }
#pragma unroll
        for (int fn = 0; fn < 2; fn++)
#pragma unroll
            for (int fm = 0; fm < 2; fm++)
                acc[fn][fm] = __builtin_amdgcn_mfma_f32_16x16x32_bf16(
                    bq[kb % 3][fn], af[fm], acc[fn][fm], 0, 0, 0);
    }
#pragma unroll
    for (int fn = 0; fn < 2; fn++) {
        const int k0 = w * 32 + fn * 16 + lg * 4;     // output col = next-layer k
        const int kc = k0 >> 3, kj = k0 & 7;
#pragma unroll
        for (int fm = 0; fm < 2; fm++) {
            const int m = fm * 16 + lr;
            float v0 = fmaxf(acc[fn][fm][0] + b4[fn].x, 0.f);
            float v1 = fmaxf(acc[fn][fm][1] + b4[fn].y, 0.f);
            float v2 = fmaxf(acc[fn][fm][2] + b4[fn].z, 0.f);
            float v3 = fmaxf(acc[fn][fm][3] + b4[fn].w, 0.f);
            uint2 q = { cvt_pk_bf16(v0, v1), cvt_pk_bf16(v2, v3) };
            *(uint2*)&Ad[m * 256 + ((kc ^ (m & 7)) * 8) + kj] = q;
        }
    }
}

__device__ __forceinline__ void layer_e1(
    const ushort_t* __restrict__ wE, const float* __restrict__ bE,
    const ushort_t* __restrict__ As, ushort_t* __restrict__ UVb,
    const int m0, const int w, const int lr, const int lg)
{
    const ushort_t* wimg = (w < 4) ? wE : (wE + 65536);
    const int nb = (w & 3) * 64;
    int boffs[4]; float4 b4[4];
#pragma unroll
    for (int fn = 0; fn < 4; fn++) {
        const int n = nb + fn * 16 + lr;
        boffs[fn] = n * 32 + ((lg ^ ((lr >> 1) & 3)) * 8);
        if (w < 4) b4[fn] = *(const float4*)&bE[nb + fn * 16 + lg * 4];
        else       b4[fn] = make_float4(0.f, 0.f, 0.f, 0.f);
    }
    bf16x8 bq[3][4];
#pragma unroll
    for (int fn = 0; fn < 4; fn++) bq[0][fn] = *(const bf16x8*)&wimg[boffs[fn]];
#pragma unroll
    for (int fn = 0; fn < 4; fn++) bq[1][fn] = *(const bf16x8*)&wimg[8192 + boffs[fn]];
    f32x4 acc[4][2] = {};
#pragma unroll
    for (int kb = 0; kb < 8; kb++) {
        if (kb < 6)
#pragma unroll
            for (int fn = 0; fn < 4; fn++)
                bq[(kb + 2) % 3][fn] = *(const bf16x8*)&wimg[(kb + 2) * 8192 + boffs[fn]];
        bf16x8 af[2];
#pragma unroll
        for (int fm = 0; fm < 2; fm++) {
            const int r = fm * 16 + lr;
            af[fm] = *(const bf16x8*)&As[r * 256 + (((kb * 4 + lg) ^ (r & 7)) * 8)];
        }
#pragma unroll
        for (int fn = 0; fn < 4; fn++)
#pragma unroll
            for (int fm = 0; fm < 2; fm++)
                acc[fn][fm] = __builtin_amdgcn_mfma_f32_16x16x32_bf16(
                    bq[kb % 3][fn], af[fm], acc[fn][fm], 0, 0, 0);
    }
#pragma unroll
    for (int fn = 0; fn < 4; fn++) {
        const int nglob = w * 64 + fn * 16 + lg * 4;
#pragma unroll
        for (int fm = 0; fm < 2; fm++) {
            const int node = m0 + fm * 16 + lr;
            float v0 = acc[fn][fm][0] + b4[fn].x;
            float v1 = acc[fn][fm][1] + b4[fn].y;
            float v2 = acc[fn][fm][2] + b4[fn].z;
            float v3 = acc[fn][fm][3] + b4[fn].w;
            uint2 q = { cvt_pk_bf16(v0, v1), cvt_pk_bf16(v2, v3) };
            *(uint2*)&UVb[(size_t)node * 512 + nglob] = q;
        }
    }
}

__device__ __forceinline__ void layer_fin(
    const ushort_t* __restrict__ wimg, const float* __restrict__ bias,
    const ushort_t* __restrict__ As, float* __restrict__ out,
    const int m0, const int w, const int lr, const int lg)
{
    int boffs[2]; float4 b4[2];
#pragma unroll
    for (int fn = 0; fn < 2; fn++) {
        const int n = w * 32 + fn * 16 + lr;
        boffs[fn] = n * 32 + ((lg ^ ((lr >> 1) & 3)) * 8);
        b4[fn] = *(const float4*)&bias[w * 32 + fn * 16 + lg * 4];
    }
    bf16x8 bq[3][2];
#pragma unroll
    for (int fn = 0; fn < 2; fn++) bq[0][fn] = *(const bf16x8*)&wimg[boffs[fn]];
#pragma unroll
    for (int fn = 0; fn < 2; fn++) bq[1][fn] = *(const bf16x8*)&wimg[8192 + boffs[fn]];
    f32x4 acc[2][2] = {};
#pragma unroll
    for (int kb = 0; kb < 8; kb++) {
        if (kb < 6)
#pragma unroll
            for (int fn = 0; fn < 2; fn++)
                bq[(kb + 2) % 3][fn] = *(const bf16x8*)&wimg[(kb + 2) * 8192 + boffs[fn]];
        bf16x8 af[2];
#pragma unroll
        for (int fm = 0; fm < 2; fm++) {
            const int r = fm * 16 + lr;
            af[fm] = *(const bf16x8*)&As[r * 256 + (((kb * 4 + lg) ^ (r & 7)) * 8)];
        }
#pragma unroll
        for (int fn = 0; fn < 2; fn++)
#pragma unroll
            for (int fm = 0; fm < 2; fm++)
                acc[fn][fm] = __builtin_amdgcn_mfma_f32_16x16x32_bf16(
                    bq[kb % 3][fn], af[fm], acc[fn][fm], 0, 0, 0);
    }
#pragma unroll
    for (int fn = 0; fn < 2; fn++) {
        const int col = w * 32 + fn * 16 + lg * 4;
#pragma unroll
        for (int fm = 0; fm < 2; fm++) {
            const int row = m0 + fm * 16 + lr;
            float4 o;
            o.x = fmaxf(acc[fn][fm][0] + b4[fn].x, 0.f);
            o.y = fmaxf(acc[fn][fm][1] + b4[fn].y, 0.f);
            o.z = fmaxf(acc[fn][fm][2] + b4[fn].z, 0.f);
            o.w = fmaxf(acc[fn][fm][3] + b4[fn].w, 0.f);
            *(float4*)&out[(size_t)row * 256 + col] = o;
        }
    }
}

template <int THREE>
__global__ __launch_bounds__(512, 2) void mlp_chain(
    const ushort_t* __restrict__ in,
    const ushort_t* __restrict__ wA, const float* __restrict__ bA,
    const ushort_t* __restrict__ wB, const float* __restrict__ bB,
    const ushort_t* __restrict__ wE, const float* __restrict__ bE,
    void* __restrict__ out)
{
    __shared__ ushort_t A0[32 * 256];
    __shared__ ushort_t A1[32 * 256];
    const int m0 = blockIdx.x * 32;
    const int t = threadIdx.x;
    const int lane = t & 63, w = t >> 6;
    const int lr = lane & 15, lg = lane >> 4;

    {
        const int r0 = t >> 5, p0 = t & 31;
        gload16(in + (size_t)(m0 + r0) * 256 + ((p0 ^ (r0 & 7)) * 8), &A0[t * 8]);
        const int r1 = r0 + 16;
        gload16(in + (size_t)(m0 + r1) * 256 + ((p0 ^ (r1 & 7)) * 8), &A0[(t + 512) * 8]);
    }
    __syncthreads();

    layer_to_lds(wA, bA, A0, A1, w, lr, lg);
    __syncthreads();
    if constexpr (THREE) {
        layer_to_lds(wB, bB, A1, A0, w, lr, lg);
        __syncthreads();
        layer_e1(wE, bE, A0, (ushort_t*)out, m0, w, lr, lg);
    } else {
        layer_fin(wB, bB, A1, (float*)out, m0, w, lr, lg);
    }
}

// ---------------------------------------------------------------------------
// Fused edge layer-2 + scatter-mean, v16: 32x32x16 MFMA.
// Grid 2048 x 256 thr (4 waves). Block = (batch, quad of 4 receivers):
// 128 virtual rows (4 recv x 32 slots, slot31 dummy) x N=256.
// Wave w owns cols [w*64, w*64+64): 4 m-tiles x 2 n-tiles of 32x32,
// acc = f32x16[4][2] (128 AGPRs). A tile [128][64] bf16 chunk-swizzled,
// dbuf 2x16KB; B-frags from L2-resident swizzled image, post-streak prefetch;
// soft (lgkm-only) barrier.
__global__ __launch_bounds__(256, 2) void edge_fused(
    const ushort_t* __restrict__ UVb,   // [8192][512] bf16: U'(+b_e1) | V
    const ushort_t* __restrict__ WBsw,  // swizzled w_e2 image
    const float* __restrict__ b2,
    ushort_t* __restrict__ agg)         // [8192][256] bf16
{
    __shared__ ushort_t As[2][128 * 64];   // 16KB each

    const int logical = (blockIdx.x & 7) * 256 + (blockIdx.x >> 3);  // 2048%8==0
    const int bb = logical >> 3;        // batch
    const int g0 = (logical & 7) * 4;   // first receiver of the quad
    const int t = threadIdx.x;
    const int lane = t & 63;
    const int w = t >> 6;
    const int l31 = lane & 31;
    const int hg = lane >> 5;           // k half-granule select

    const int brow = t >> 1;            // 0..127
    const int kh = t & 1;
    const int jr = brow >> 5;
    const int s = brow & 31;
    const int j = g0 + jr;
    const int si = (s == 31) ? j : (s + (s >= j ? 1 : 0));
    const ushort_t* up = UVb + (size_t)(bb * 32 + si) * 512 + kh * 32;
    const ushort_t* vp = UVb + (size_t)(bb * 32 + j) * 512 + 256 + kh * 32;
    const int rs7 = brow & 7;
    int aw[4];
#pragma unroll
    for (int i = 0; i < 4; i++)
        aw[i] = brow * 64 + (((kh * 4 + i) ^ rs7) * 8);

    int abase[4];
#pragma unroll
    for (int mt = 0; mt < 4; mt++) abase[mt] = (mt * 32 + l31) * 64;
    const int r7 = l31 & 7;
    int nb32[2], nsw[2];
#pragma unroll
    for (int nt = 0; nt < 2; nt++) {
        const int n = w * 64 + nt * 32 + l31;
        nb32[nt] = n * 32;
        nsw[nt] = (n >> 1) & 3;
    }

    auto build = [&](int buf, const uint4* u, const uint4* v) {
#pragma unroll
        for (int i = 0; i < 4; i++) {
            uint4 q;
            q.x = cvt_pk_bf16(fmaxf(lo16f(u[i].x) + lo16f(v[i].x), 0.f),
                              fmaxf(hi16f(u[i].x) + hi16f(v[i].x), 0.f));
            q.y = cvt_pk_bf16(fmaxf(lo16f(u[i].y) + lo16f(v[i].y), 0.f),
                              fmaxf(hi16f(u[i].y) + hi16f(v[i].y), 0.f));
            q.z = cvt_pk_bf16(fmaxf(lo16f(u[i].z) + lo16f(v[i].z), 0.f),
                              fmaxf(hi16f(u[i].z) + hi16f(v[i].z), 0.f));
            q.w = cvt_pk_bf16(fmaxf(lo16f(u[i].w) + lo16f(v[i].w), 0.f),
                              fmaxf(hi16f(u[i].w) + hi16f(v[i].w), 0.f));
            *(uint4*)&As[buf][aw[i]] = q;
        }
    };

    auto loadB = [&](int kb, bf16x8 dst[4][2]) {
#pragma unroll
        for (int k16 = 0; k16 < 4; k16++)
#pragma unroll
            for (int nt = 0; nt < 2; nt++) {
                const int kq = kb * 2 + (k16 >> 1);
                const int kc = (k16 & 1) * 2 + hg;
                dst[k16][nt] = *(const bf16x8*)&WBsw[kq * 8192 + nb32[nt]
                                                    + ((kc ^ nsw[nt]) * 8)];
            }
    };

    {
        uint4 u[4], v[4];
#pragma unroll
        for (int i = 0; i < 4; i++) {
            u[i] = *(const uint4*)(up + i * 8);
            v[i] = *(const uint4*)(vp + i * 8);
        }
        build(0, u, v);
    }
    bf16x8 bc[4][2];
    loadB(0, bc);

    f32x16 acc[4][2] = {};

#pragma unroll
    for (int kb = 0; kb < 4; kb++) {
        const int cur = kb & 1;
        soft_barrier();
        uint4 u[4], v[4];
        if (kb < 3) {
            const ushort_t* upn = up + (kb + 1) * 64;
            const ushort_t* vpn = vp + (kb + 1) * 64;
#pragma unroll
            for (int i = 0; i < 4; i++) {
                u[i] = *(const uint4*)(upn + i * 8);
                v[i] = *(const uint4*)(vpn + i * 8);
            }
        }
        __builtin_amdgcn_s_setprio(1);
#pragma unroll
        for (int k16 = 0; k16 < 4; k16++) {
            const int goff = (((k16 * 2 + hg) ^ r7) * 8);
            bf16x8 af[4];
#pragma unroll
            for (int mt = 0; mt < 4; mt++)
                af[mt] = *(const bf16x8*)&As[cur][abase[mt] + goff];
#pragma unroll
            for (int nt = 0; nt < 2; nt++)
#pragma unroll
                for (int mt = 0; mt < 4; mt++)
                    acc[mt][nt] = __builtin_amdgcn_mfma_f32_32x32x16_bf16(
                        af[mt], bc[k16][nt], acc[mt][nt], 0, 0, 0);
        }
        __builtin_amdgcn_s_setprio(0);
        if (kb < 3) {
            loadB(kb + 1, bc);
            build(cur ^ 1, u, v);
        }
    }

    // Epilogue: bias+relu, sum 31 real slots, /31, bf16 out.
    // C/D: col = lane&31, slot = (j&3) + 8*(j>>2) + 4*hg; slot31 = reg15 hi.
#pragma unroll
    for (int nt = 0; nt < 2; nt++) {
        const int col = w * 64 + nt * 32 + l31;
        const float bvf = b2[col];
#pragma unroll
        for (int mt = 0; mt < 4; mt++) {
            float sum = 0.f;
#pragma unroll
            for (int jj = 0; jj < 16; jj++) {
                float v = fmaxf(acc[mt][nt][jj] + bvf, 0.f);
                if (!(jj == 15 && hg == 1)) sum += v;   // skip slot 31
            }
            sum += __shfl_xor(sum, 32);
            if (lane < 32)
                agg[(size_t)(bb * 32 + g0 + mt) * 256 + col] =
                    f2bf(sum * (1.0f / 31.0f));
        }
    }
}

// ---------------------------------------------------------------------------
extern "C" void kernel_launch(void* const* d_in, const int* in_sizes, int n_in,
                              void* d_out, int out_size, void* d_ws, size_t ws_size,
                              hipStream_t stream)
{
    const float* x     = (const float*)d_in[0];
    const float* w_in1 = (const float*)d_in[3];
    const float* b_in1 = (const float*)d_in[4];
    const float* w_in2 = (const float*)d_in[5];
    const float* b_in2 = (const float*)d_in[6];
    const float* w_e1  = (const float*)d_in[7];
    const float* b_e1  = (const float*)d_in[8];
    const float* w_e2  = (const float*)d_in[9];
    const float* b_e2  = (const float*)d_in[10];
    const float* w_n1  = (const float*)d_in[11];
    const float* b_n1  = (const float*)d_in[12];
    const float* w_n2  = (const float*)d_in[13];
    const float* b_n2  = (const float*)d_in[14];

    char* ws = (char*)d_ws;
    size_t off = 0;
    auto alloc = [&](size_t n) { char* p = ws + off; off += (n + 255) & ~(size_t)255; return p; };

    ushort_t* wt  = (ushort_t*)alloc(7 * 65536 * sizeof(ushort_t));
    ushort_t* xb  = (ushort_t*)alloc(8192 * 256 * 2);
    ushort_t* UVb = (ushort_t*)alloc(8192 * 512 * 2);
    ushort_t* ag  = (ushort_t*)alloc(8192 * 256 * 2);
    (void)ws_size; (void)in_sizes; (void)n_in; (void)out_size;

    prep_all<<<1080, 256, 0, stream>>>(w_in1, w_in2, w_e1, w_e2, w_n1, w_n2, wt, x, xb);

    // pass 0 front: in1 -> in2 -> e1
    mlp_chain<1><<<256, 512, 0, stream>>>(xb,
        wt + 0 * 65536, b_in1, wt + 1 * 65536, b_in2, wt + 2 * 65536, b_e1, UVb);
    edge_fused<<<2048, 256, 0, stream>>>(UVb, wt + 4 * 65536, b_e2, ag);
    // pass 1 front: n1 -> n2 -> e1
    mlp_chain<1><<<256, 512, 0, stream>>>(ag,
        wt + 5 * 65536, b_n1, wt + 6 * 65536, b_n2, wt + 2 * 65536, b_e1, UVb);
    edge_fused<<<2048, 256, 0, stream>>>(UVb, wt + 4 * 65536, b_e2, ag);
    // final: n1 -> n2 (f32 out)
    mlp_chain<0><<<256, 512, 0, stream>>>(ag,
        wt + 5 * 65536, b_n1, wt + 6 * 65536, b_n2, nullptr, nullptr, d_out);
}